// Round 3
// baseline (258.386 us; speedup 1.0000x reference)
//
#include <hip/hip_runtime.h>

#define NB 15
#define NV 17          // focal, cp, 15 bins
#define GRID 4096
#define BLOCK 256

// partials layout in ws: partials[j * GRID + block], j in [0,17)
// j=0: focal sum, j=1: cp sum, j=2..16: per-bin sum(t - p)

__device__ __forceinline__ void process_elem(float pk, float uk, int tk,
                                             float& facc, float& cacc,
                                             float* __restrict__ lbins)
{
    bool pos = (tk == 1);

    // focal: -alpha * (1-pt)^2 * log(pt + 1e-12)
    float pt    = pos ? pk : 1.0f - pk;
    float alpha = pos ? 1.0f : 2.0f;
    float om    = 1.0f - pt;
    facc -= alpha * om * om * __logf(pt + 1e-12f);

    // calibration penalty
    float w   = 1.0f - uk;
    float pen = pos ? ((pk < 0.7f) ? uk * uk : 0.0f)
                    : ((pk > 0.7f) ? w * w : 0.0f);
    cacc += pen;

    // ECE histogram: lane-private LDS slice, ds_add_f32 (no return -> no
    // latency chain, no contention: each lane owns its 15 floats)
    int b = (int)ceilf(pk * 15.0f) - 1;
    b = (b < 0) ? 0 : ((b > NB - 1) ? NB - 1 : b);
    float v = (pos ? 1.0f : 0.0f) - pk;
    atomicAdd(&lbins[b], v);
}

__global__ __launch_bounds__(BLOCK) void fcl_main(
    const float* __restrict__ p_hat,
    const float* __restrict__ u_hat,
    const int*   __restrict__ targets,
    float* __restrict__ partials,
    int n4, int n)
{
    // lane-private histograms, stride 15 (coprime with 32 banks)
    __shared__ float sbins[BLOCK * NB];
    for (int i = threadIdx.x; i < BLOCK * NB; i += BLOCK) sbins[i] = 0.0f;
    __syncthreads();
    float* __restrict__ lbins = &sbins[threadIdx.x * NB];

    float facc = 0.0f, cacc = 0.0f;

    const float4* __restrict__ p4 = (const float4*)p_hat;
    const float4* __restrict__ u4 = (const float4*)u_hat;
    const int4*   __restrict__ t4 = (const int4*)targets;

    const int stride = gridDim.x * blockDim.x;
    int i = blockIdx.x * blockDim.x + threadIdx.x;

    for (; i + stride < n4; i += 2 * stride) {
        float4 p0 = p4[i];          float4 p1 = p4[i + stride];
        float4 u0 = u4[i];          float4 u1 = u4[i + stride];
        int4   t0 = t4[i];          int4   t1 = t4[i + stride];
        #pragma unroll
        for (int k = 0; k < 4; ++k)
            process_elem((&p0.x)[k], (&u0.x)[k], (&t0.x)[k], facc, cacc, lbins);
        #pragma unroll
        for (int k = 0; k < 4; ++k)
            process_elem((&p1.x)[k], (&u1.x)[k], (&t1.x)[k], facc, cacc, lbins);
    }
    if (i < n4) {
        float4 p0 = p4[i]; float4 u0 = u4[i]; int4 t0 = t4[i];
        #pragma unroll
        for (int k = 0; k < 4; ++k)
            process_elem((&p0.x)[k], (&u0.x)[k], (&t0.x)[k], facc, cacc, lbins);
    }

    // scalar tail (n not multiple of 4)
    if (blockIdx.x == 0 && threadIdx.x == 0) {
        for (int j = n4 * 4; j < n; ++j)
            process_elem(p_hat[j], u_hat[j], targets[j], facc, cacc, lbins);
    }

    __syncthreads();   // drain ds_adds (each thread reads only its own slice)

    float vals[NV];
    vals[0] = facc; vals[1] = cacc;
    #pragma unroll
    for (int j = 0; j < NB; ++j) vals[2 + j] = lbins[j];

    #pragma unroll
    for (int off = 32; off > 0; off >>= 1) {
        #pragma unroll
        for (int j = 0; j < NV; ++j)
            vals[j] += __shfl_down(vals[j], off, 64);
    }

    __shared__ float lds[BLOCK / 64][NV];
    const int wave = threadIdx.x >> 6;
    const int lane = threadIdx.x & 63;
    if (lane == 0) {
        #pragma unroll
        for (int j = 0; j < NV; ++j) lds[wave][j] = vals[j];
    }
    __syncthreads();

    if (threadIdx.x < NV) {
        float s = 0.0f;
        #pragma unroll
        for (int w = 0; w < BLOCK / 64; ++w) s += lds[w][threadIdx.x];
        partials[threadIdx.x * gridDim.x + blockIdx.x] = s;
    }
}

__global__ __launch_bounds__(1024) void fcl_final(
    const float* __restrict__ partials,
    float* __restrict__ out, float inv_n, int grid)
{
    const int t = threadIdx.x;
    float v[NV];
    #pragma unroll
    for (int j = 0; j < NV; ++j) {
        float s = 0.0f;
        for (int i = t; i < grid; i += 1024) s += partials[j * grid + i];
        v[j] = s;
    }

    #pragma unroll
    for (int off = 32; off > 0; off >>= 1) {
        #pragma unroll
        for (int j = 0; j < NV; ++j)
            v[j] += __shfl_down(v[j], off, 64);
    }

    __shared__ float lds[16][NV];
    const int wave = t >> 6;
    const int lane = t & 63;
    if (lane == 0) {
        #pragma unroll
        for (int j = 0; j < NV; ++j) lds[wave][j] = v[j];
    }
    __syncthreads();

    if (t == 0) {
        float s[NV];
        #pragma unroll
        for (int j = 0; j < NV; ++j) s[j] = 0.0f;
        for (int w = 0; w < 16; ++w)
            #pragma unroll
            for (int j = 0; j < NV; ++j) s[j] += lds[w][j];
        float e = 0.0f;
        #pragma unroll
        for (int b = 0; b < NB; ++b) e += fabsf(s[2 + b]);
        out[0] = (s[0] + 6.0f * s[1] + 5.0f * e) * inv_n;
    }
}

extern "C" void kernel_launch(void* const* d_in, const int* in_sizes, int n_in,
                              void* d_out, int out_size, void* d_ws, size_t ws_size,
                              hipStream_t stream) {
    const float* p = (const float*)d_in[0];
    const float* u = (const float*)d_in[1];
    const int*   t = (const int*)d_in[2];
    float* out = (float*)d_out;
    float* ws  = (float*)d_ws;

    const int n  = in_sizes[0];
    const int n4 = n / 4;

    fcl_main<<<GRID, BLOCK, 0, stream>>>(p, u, t, ws, n4, n);
    fcl_final<<<1, 1024, 0, stream>>>(ws, out, 1.0f / (float)n, GRID);
}

// Round 4
// 230.836 us; speedup vs baseline: 1.1193x; 1.1193x over previous
//
#include <hip/hip_runtime.h>

#define NB 15
#define NV 17          // focal, cp, 15 bins
#define GRID 4096
#define BLOCK 256
#define ITERS 4        // independent float4 triplets per thread

// partials layout in ws: partials[j * GRID + block], j in [0,17)

__device__ __forceinline__ void process_elem(float pk, float uk, int tk,
                                             float& facc, float& cacc,
                                             float* bins)
{
    bool pos = (tk == 1);

    // focal: -alpha * (1-pt)^2 * log(pt + 1e-12)
    float pt    = pos ? pk : 1.0f - pk;
    float alpha = pos ? 1.0f : 2.0f;
    float om    = 1.0f - pt;
    facc -= alpha * om * om * __logf(pt + 1e-12f);

    // calibration penalty
    float w   = 1.0f - uk;
    float pen = pos ? ((pk < 0.7f) ? uk * uk : 0.0f)
                    : ((pk > 0.7f) ? w * w : 0.0f);
    cacc += pen;

    // ECE histogram into REGISTER bins (15 independent cmp/cndmask/add chains)
    int b = (int)ceilf(pk * 15.0f) - 1;
    b = (b < 0) ? 0 : ((b > NB - 1) ? NB - 1 : b);
    float v = (pos ? 1.0f : 0.0f) - pk;
    #pragma unroll
    for (int j = 0; j < NB; ++j)
        bins[j] += (b == j) ? v : 0.0f;
}

__global__ __launch_bounds__(BLOCK) void fcl_main(
    const float* __restrict__ p_hat,
    const float* __restrict__ u_hat,
    const int*   __restrict__ targets,
    float* __restrict__ partials,
    int n4, int n)
{
    float bins[NB];
    #pragma unroll
    for (int j = 0; j < NB; ++j) bins[j] = 0.0f;
    float facc = 0.0f, cacc = 0.0f;

    const float4* __restrict__ p4 = (const float4*)p_hat;
    const float4* __restrict__ u4 = (const float4*)u_hat;
    const int4*   __restrict__ t4 = (const int4*)targets;

    const int total = GRID * BLOCK;
    int i = blockIdx.x * BLOCK + threadIdx.x;

    // fast path: ITERS independent float4 triplets, all loads issued up front
    for (; i + (ITERS - 1) * total < n4; i += ITERS * total) {
        float4 p[ITERS]; float4 u[ITERS]; int4 t[ITERS];
        #pragma unroll
        for (int j = 0; j < ITERS; ++j) {
            p[j] = p4[i + j * total];
            u[j] = u4[i + j * total];
            t[j] = t4[i + j * total];
        }
        #pragma unroll
        for (int j = 0; j < ITERS; ++j) {
            #pragma unroll
            for (int k = 0; k < 4; ++k)
                process_elem((&p[j].x)[k], (&u[j].x)[k], (&t[j].x)[k],
                             facc, cacc, bins);
        }
    }
    // remainder float4s
    for (; i < n4; i += total) {
        float4 p0 = p4[i]; float4 u0 = u4[i]; int4 t0 = t4[i];
        #pragma unroll
        for (int k = 0; k < 4; ++k)
            process_elem((&p0.x)[k], (&u0.x)[k], (&t0.x)[k], facc, cacc, bins);
    }

    // scalar tail (n not multiple of 4)
    if (blockIdx.x == 0 && threadIdx.x == 0) {
        for (int j = n4 * 4; j < n; ++j)
            process_elem(p_hat[j], u_hat[j], targets[j], facc, cacc, bins);
    }

    // wave-64 shuffle reduction of all 17 values
    float vals[NV];
    vals[0] = facc; vals[1] = cacc;
    #pragma unroll
    for (int j = 0; j < NB; ++j) vals[2 + j] = bins[j];

    #pragma unroll
    for (int off = 32; off > 0; off >>= 1) {
        #pragma unroll
        for (int j = 0; j < NV; ++j)
            vals[j] += __shfl_down(vals[j], off, 64);
    }

    __shared__ float lds[BLOCK / 64][NV];
    const int wave = threadIdx.x >> 6;
    const int lane = threadIdx.x & 63;
    if (lane == 0) {
        #pragma unroll
        for (int j = 0; j < NV; ++j) lds[wave][j] = vals[j];
    }
    __syncthreads();

    if (threadIdx.x < NV) {
        float s = 0.0f;
        #pragma unroll
        for (int w = 0; w < BLOCK / 64; ++w) s += lds[w][threadIdx.x];
        partials[threadIdx.x * gridDim.x + blockIdx.x] = s;
    }
}

__global__ __launch_bounds__(1024) void fcl_final(
    const float* __restrict__ partials,
    float* __restrict__ out, float inv_n, int grid)
{
    const int t = threadIdx.x;
    float v[NV];
    #pragma unroll
    for (int j = 0; j < NV; ++j) {
        float s = 0.0f;
        for (int i = t; i < grid; i += 1024) s += partials[j * grid + i];
        v[j] = s;
    }

    #pragma unroll
    for (int off = 32; off > 0; off >>= 1) {
        #pragma unroll
        for (int j = 0; j < NV; ++j)
            v[j] += __shfl_down(v[j], off, 64);
    }

    __shared__ float lds[16][NV];
    const int wave = t >> 6;
    const int lane = t & 63;
    if (lane == 0) {
        #pragma unroll
        for (int j = 0; j < NV; ++j) lds[wave][j] = v[j];
    }
    __syncthreads();

    if (t == 0) {
        float s[NV];
        #pragma unroll
        for (int j = 0; j < NV; ++j) s[j] = 0.0f;
        for (int w = 0; w < 16; ++w)
            #pragma unroll
            for (int j = 0; j < NV; ++j) s[j] += lds[w][j];
        float e = 0.0f;
        #pragma unroll
        for (int b = 0; b < NB; ++b) e += fabsf(s[2 + b]);
        out[0] = (s[0] + 6.0f * s[1] + 5.0f * e) * inv_n;
    }
}

extern "C" void kernel_launch(void* const* d_in, const int* in_sizes, int n_in,
                              void* d_out, int out_size, void* d_ws, size_t ws_size,
                              hipStream_t stream) {
    const float* p = (const float*)d_in[0];
    const float* u = (const float*)d_in[1];
    const int*   t = (const int*)d_in[2];
    float* out = (float*)d_out;
    float* ws  = (float*)d_ws;

    const int n  = in_sizes[0];
    const int n4 = n / 4;

    fcl_main<<<GRID, BLOCK, 0, stream>>>(p, u, t, ws, n4, n);
    fcl_final<<<1, 1024, 0, stream>>>(ws, out, 1.0f / (float)n, GRID);
}

// Round 5
// 215.733 us; speedup vs baseline: 1.1977x; 1.0700x over previous
//
#include <hip/hip_runtime.h>

#define NB 15
#define NV 17          // focal, cp, 15 bins
#define GRID 2048      // exactly 8 blocks/CU on 256 CUs -> 32 waves/CU, one tranche
#define BLOCK 256

// partials layout in ws: partials[j * GRID + block], j in [0,17)

__device__ __forceinline__ void process_elem(float pk, float uk, int tk,
                                             float& facc, float& cacc,
                                             float* bins)
{
    bool pos = (tk == 1);
    float q = 1.0f - pk;             // shared: pt (neg branch) and t-p (pos branch)

    // focal: -alpha * (1-pt)^2 * log(pt + 1e-12), alpha = pos?1:2
    float pt = pos ? pk : q;
    float om = 1.0f - pt;
    float s  = om * om;
    float sa = pos ? s : (s + s);    // alpha*om^2
    float l  = __logf(pt + 1e-12f);
    facc = fmaf(-sa, l, facc);

    // calibration penalty
    float w  = 1.0f - uk;
    float a  = (pk < 0.7f) ? uk * uk : 0.0f;
    float b2 = (pk > 0.7f) ? w * w : 0.0f;
    cacc += pos ? a : b2;

    // ECE: bin = clip(ceil(p*15)-1, 0, 14); v = t - p = pos ? 1-p : -p
    int b = (int)ceilf(pk * 15.0f) - 1;
    b = (b < 0) ? 0 : ((b > NB - 1) ? NB - 1 : b);
    float v = pos ? q : -pk;
    #pragma unroll
    for (int j = 0; j < NB; ++j)
        bins[j] += (b == j) ? v : 0.0f;
}

__global__ __launch_bounds__(BLOCK) void fcl_main(
    const float* __restrict__ p_hat,
    const float* __restrict__ u_hat,
    const int*   __restrict__ targets,
    float* __restrict__ partials,
    int n4, int n)
{
    float bins[NB];
    #pragma unroll
    for (int j = 0; j < NB; ++j) bins[j] = 0.0f;
    float facc = 0.0f, cacc = 0.0f;

    const float4* __restrict__ p4 = (const float4*)p_hat;
    const float4* __restrict__ u4 = (const float4*)u_hat;
    const int4*   __restrict__ t4 = (const int4*)targets;

    const int stride = GRID * BLOCK;
    int i = blockIdx.x * BLOCK + threadIdx.x;

    // 2x unrolled grid-stride (for n=16.7M: exactly 4 iterations, no remainder)
    for (; i + stride < n4; i += 2 * stride) {
        float4 p0 = p4[i];          float4 p1 = p4[i + stride];
        float4 u0 = u4[i];          float4 u1 = u4[i + stride];
        int4   t0 = t4[i];          int4   t1 = t4[i + stride];
        #pragma unroll
        for (int k = 0; k < 4; ++k)
            process_elem((&p0.x)[k], (&u0.x)[k], (&t0.x)[k], facc, cacc, bins);
        #pragma unroll
        for (int k = 0; k < 4; ++k)
            process_elem((&p1.x)[k], (&u1.x)[k], (&t1.x)[k], facc, cacc, bins);
    }
    if (i < n4) {
        float4 p0 = p4[i]; float4 u0 = u4[i]; int4 t0 = t4[i];
        #pragma unroll
        for (int k = 0; k < 4; ++k)
            process_elem((&p0.x)[k], (&u0.x)[k], (&t0.x)[k], facc, cacc, bins);
    }

    // scalar tail (n not multiple of 4)
    if (blockIdx.x == 0 && threadIdx.x == 0) {
        for (int j = n4 * 4; j < n; ++j)
            process_elem(p_hat[j], u_hat[j], targets[j], facc, cacc, bins);
    }

    // wave-64 shuffle reduction of all 17 values
    float vals[NV];
    vals[0] = facc; vals[1] = cacc;
    #pragma unroll
    for (int j = 0; j < NB; ++j) vals[2 + j] = bins[j];

    #pragma unroll
    for (int off = 32; off > 0; off >>= 1) {
        #pragma unroll
        for (int j = 0; j < NV; ++j)
            vals[j] += __shfl_down(vals[j], off, 64);
    }

    __shared__ float lds[BLOCK / 64][NV];
    const int wave = threadIdx.x >> 6;
    const int lane = threadIdx.x & 63;
    if (lane == 0) {
        #pragma unroll
        for (int j = 0; j < NV; ++j) lds[wave][j] = vals[j];
    }
    __syncthreads();

    if (threadIdx.x < NV) {
        float s = 0.0f;
        #pragma unroll
        for (int w = 0; w < BLOCK / 64; ++w) s += lds[w][threadIdx.x];
        partials[threadIdx.x * GRID + blockIdx.x] = s;
    }
}

__global__ __launch_bounds__(1024) void fcl_final(
    const float* __restrict__ partials,
    float* __restrict__ out, float inv_n, int grid)
{
    const int t = threadIdx.x;
    float v[NV];
    #pragma unroll
    for (int j = 0; j < NV; ++j) {
        float s = 0.0f;
        for (int i = t; i < grid; i += 1024) s += partials[j * grid + i];
        v[j] = s;
    }

    #pragma unroll
    for (int off = 32; off > 0; off >>= 1) {
        #pragma unroll
        for (int j = 0; j < NV; ++j)
            v[j] += __shfl_down(v[j], off, 64);
    }

    __shared__ float lds[16][NV];
    const int wave = t >> 6;
    const int lane = t & 63;
    if (lane == 0) {
        #pragma unroll
        for (int j = 0; j < NV; ++j) lds[wave][j] = v[j];
    }
    __syncthreads();

    if (t == 0) {
        float s[NV];
        #pragma unroll
        for (int j = 0; j < NV; ++j) s[j] = 0.0f;
        for (int w = 0; w < 16; ++w)
            #pragma unroll
            for (int j = 0; j < NV; ++j) s[j] += lds[w][j];
        float e = 0.0f;
        #pragma unroll
        for (int b = 0; b < NB; ++b) e += fabsf(s[2 + b]);
        out[0] = (s[0] + 6.0f * s[1] + 5.0f * e) * inv_n;
    }
}

extern "C" void kernel_launch(void* const* d_in, const int* in_sizes, int n_in,
                              void* d_out, int out_size, void* d_ws, size_t ws_size,
                              hipStream_t stream) {
    const float* p = (const float*)d_in[0];
    const float* u = (const float*)d_in[1];
    const int*   t = (const int*)d_in[2];
    float* out = (float*)d_out;
    float* ws  = (float*)d_ws;

    const int n  = in_sizes[0];
    const int n4 = n / 4;

    fcl_main<<<GRID, BLOCK, 0, stream>>>(p, u, t, ws, n4, n);
    fcl_final<<<1, 1024, 0, stream>>>(ws, out, 1.0f / (float)n, GRID);
}